// Round 2
// baseline (64.950 us; speedup 1.0000x reference)
//
#include <hip/hip_runtime.h>

// Problem constants (match the reference)
#define BATCH 64
#define FDIM  16
#define NDIM  128
#define FP    32
#define NEDGE (NDIM * (NDIM - 1))   // 16256
#define NEDGE4 (NEDGE / 4)          // 4064  (NEDGE % 4 == 0)

// out[b,e] = s1[b, recv[e]] + s2[b, send[e]]
//   s1[b,n] = sum_f x[b,f,n] * v1[f],  v1[f] = sum_g a[g]      * w[g,f]
//   s2[b,n] = sum_f x[b,f,n] * v2[f],  v2[f] = sum_g a[FP + g] * w[g,f]
// Edge list is the deterministic row-major (r,s) r!=s enumeration:
//   e = r*127 + k,  s = k + (k >= r)   -- so recv/send need not be loaded.
__global__ __launch_bounds__(256) void gat_edge_fused(
    const float* __restrict__ x,     // (B, F, N)
    const float* __restrict__ w,     // (FP, F)
    const float* __restrict__ a,     // (2*FP)
    float*       __restrict__ out)   // (B, NEDGE)
{
    __shared__ float s1s[NDIM];
    __shared__ float s2s[NDIM];

    const int b = blockIdx.y;
    const int t = threadIdx.x;
    const int lane = t & 63;

    // Phase 1 (per-wave, NO barrier): lane l holds
    //   l in [0,16):  v1[l]      l in [16,32): v2[l-16]
    //   lanes 32..63 hold duplicates (harmless; shfl sources are lanes 0..31)
    const int f0 = lane & 15;
    const float* av = a + ((lane & 16) ? FP : 0);
    float vv = 0.f;
#pragma unroll
    for (int g = 0; g < FP; ++g)
        vv += av[g] * w[g * FDIM + f0];

    // Phase 2: waves 0-1 compute s1[node], waves 2-3 compute s2[node].
    // x reads are fully coalesced (64 consecutive floats per wave per f).
    const int node = t & 127;
    const int base = (t >> 7) << 4;           // 0 -> v1 lanes, 16 -> v2 lanes
    const float* xb = x + (size_t)b * (FDIM * NDIM) + node;
    float acc = 0.f;
#pragma unroll
    for (int f = 0; f < FDIM; ++f) {
        const float vf = __shfl(vv, base + f);
        acc += xb[f * NDIM] * vf;
    }
    if (t < 128) s1s[node] = acc;
    else         s2s[node] = acc;
    __syncthreads();

    // Phase 3: 4 consecutive edges per thread, arithmetic indices, float4 store
    const int e4 = blockIdx.x * 256 + t;
    if (e4 < NEDGE4) {
        int e = e4 * 4;
        int r = e / 127;                 // compiler emits magic-mul
        int k = e - r * 127;
        float s1v = s1s[r];
        float4 o;
        o.x = s1v + s2s[k + (k >= r)];
        if (++k == 127) { k = 0; s1v = s1s[++r]; }
        o.y = s1v + s2s[k + (k >= r)];
        if (++k == 127) { k = 0; s1v = s1s[++r]; }
        o.z = s1v + s2s[k + (k >= r)];
        if (++k == 127) { k = 0; s1v = s1s[++r]; }
        o.w = s1v + s2s[k + (k >= r)];
        ((float4*)(out + (size_t)b * NEDGE))[e4] = o;
    }
}

extern "C" void kernel_launch(void* const* d_in, const int* in_sizes, int n_in,
                              void* d_out, int out_size, void* d_ws, size_t ws_size,
                              hipStream_t stream) {
    const float* x = (const float*)d_in[0];
    const float* w = (const float*)d_in[1];
    const float* a = (const float*)d_in[2];
    float*     out = (float*)d_out;

    dim3 grid((NEDGE4 + 255) / 256, BATCH);  // (16, 64) = 1024 blocks
    gat_edge_fused<<<grid, 256, 0, stream>>>(x, w, a, out);
}

// Round 3
// 63.888 us; speedup vs baseline: 1.0166x; 1.0166x over previous
//
#include <hip/hip_runtime.h>

// Problem constants (match the reference)
#define BATCH 64
#define FDIM  16
#define NDIM  128
#define FP    32
#define NEDGE (NDIM * (NDIM - 1))   // 16256
#define NEDGE4 (NEDGE / 4)          // 4064  (NEDGE % 4 == 0)

// out[b,e] = s1[b, recv[e]] + s2[b, send[e]]
//   s1[b,n] = sum_f x[b,f,n] * v1[f],  v1[f] = sum_g a[g]      * w[g,f]
//   s2[b,n] = sum_f x[b,f,n] * v2[f],  v2[f] = sum_g a[FP + g] * w[g,f]
// Edge list is the deterministic row-major (r,s) r!=s enumeration:
//   e = r*127 + k,  s = k + (k >= r)   -- indices are pure arithmetic.
//
// Grid: (2, 64). Each block = one batch x half the edge list (8 chunks of
// 256 float4s). Phases 1-2 run once per block instead of once per chunk.
__global__ __launch_bounds__(256) void gat_edge_fused(
    const float* __restrict__ x,     // (B, F, N)
    const float* __restrict__ w,     // (FP, F)
    const float* __restrict__ a,     // (2*FP)
    float*       __restrict__ out)   // (B, NEDGE)
{
    __shared__ float s1s[NDIM];
    __shared__ float s2s[NDIM];

    const int b = blockIdx.y;
    const int t = threadIdx.x;
    const int lane = t & 63;

    // Phase 1 (per-wave, no barrier): lane l in [0,16) holds v1[l],
    // lanes [16,32) hold v2[l-16]; lanes 32..63 duplicate (shfl srcs < 32).
    const int f0 = lane & 15;
    const float* av = a + ((lane & 16) ? FP : 0);
    float vv = 0.f;
#pragma unroll
    for (int g = 0; g < FP; ++g)
        vv += av[g] * w[g * FDIM + f0];

    // Phase 2: waves 0-1 -> s1[node], waves 2-3 -> s2[node]; coalesced x.
    const int node = t & 127;
    const int base = (t >> 7) << 4;           // 0 -> v1 lanes, 16 -> v2 lanes
    const float* xb = x + (size_t)b * (FDIM * NDIM) + node;
    float acc = 0.f;
#pragma unroll
    for (int f = 0; f < FDIM; ++f) {
        const float vf = __shfl(vv, base + f);
        acc += xb[f * NDIM] * vf;
    }
    if (t < 128) s1s[node] = acc;
    else         s2s[node] = acc;
    __syncthreads();

    // Phase 3: 8 chunks of 256 float4-stores; arithmetic edge indices.
    const int e4base = blockIdx.x * 2048;                 // 0 or 2048
    const int e4lim  = min(e4base + 2048, NEDGE4);
    float4* outb = (float4*)(out + (size_t)b * NEDGE);
#pragma unroll
    for (int i = 0; i < 8; ++i) {
        const int e4 = e4base + i * 256 + t;
        if (e4 < e4lim) {
            int e = e4 * 4;
            int r = e / 127;                  // magic-mul
            int k = e - r * 127;
            float s1v = s1s[r];
            float4 o;
            o.x = s1v + s2s[k + (k >= r)];
            if (++k == 127) { k = 0; s1v = s1s[++r]; }
            o.y = s1v + s2s[k + (k >= r)];
            if (++k == 127) { k = 0; s1v = s1s[++r]; }
            o.z = s1v + s2s[k + (k >= r)];
            if (++k == 127) { k = 0; s1v = s1s[++r]; }
            o.w = s1v + s2s[k + (k >= r)];
            outb[e4] = o;
        }
    }
}

extern "C" void kernel_launch(void* const* d_in, const int* in_sizes, int n_in,
                              void* d_out, int out_size, void* d_ws, size_t ws_size,
                              hipStream_t stream) {
    const float* x = (const float*)d_in[0];
    const float* w = (const float*)d_in[1];
    const float* a = (const float*)d_in[2];
    float*     out = (float*)d_out;

    dim3 grid(2, BATCH);   // 128 blocks
    gat_edge_fused<<<grid, 256, 0, stream>>>(x, w, a, out);
}